// Round 1
// baseline (283.127 us; speedup 1.0000x reference)
//
#include <hip/hip_runtime.h>
#include <hip/hip_bf16.h>
#include <cstdint>

// PredictiveColumn: B=16384, DIN=DOUT=512, K_WTA=128, LATERAL_K=3
// Pipeline:
//   prep_k : bf16 convert W^T, W, V^T ; compact lateral band Mc[512][7]; zero ssq
//   kwta_k : per-row (1 wave/row) top-128 via bit binary search (exact top_k
//            tie-break), phi=gelu*mask, pd=phi', base = b_in+3td-4x+0.3*lat-1e-6*sign
//   gemm_k<1>: err = bf16(bu - (phi@W + b_out))
//   gemm_k<2>: fb  = bf16((err@W^T) * pd)
//   gemm_k<3>: d   = tau*eta*((bu@V) + fb + base) -> d_out, ssq += d^2
//   final_k: out = clamp(x + d*min(1,1/(||d||+1e-8)), -5, 5)   (in-place on d_out)

#define DEV static __device__ __forceinline__

typedef __attribute__((ext_vector_type(8))) short short8;   // 8 bf16 (4 VGPRs)
typedef __attribute__((ext_vector_type(4))) float f32x4;

static constexpr int BATCH = 16384;
static constexpr int D = 512;

DEV unsigned short f2bf(float f) {           // RNE float->bf16 (no NaN inputs here)
  unsigned u = __float_as_uint(f);
  return (unsigned short)((u + 0x7FFFu + ((u >> 16) & 1u)) >> 16);
}
DEV float bf2f(unsigned short h) { return __uint_as_float(((unsigned)h) << 16); }

DEV int wsum(int v)   { for (int o = 32; o; o >>= 1) v += __shfl_xor(v, o, 64); return v; }
DEV float wsumf(float v) { for (int o = 32; o; o >>= 1) v += __shfl_xor(v, o, 64); return v; }

DEV void gload16(const void* g, void* l) {
  __builtin_amdgcn_global_load_lds((const __attribute__((address_space(1))) void*)g,
                                   (__attribute__((address_space(3))) void*)l, 16, 0, 0);
}

DEV void load8(const float* rowp, int lane, float v[8]) {
  const float4* q = (const float4*)rowp;
  float4 a = q[lane * 2], b = q[lane * 2 + 1];
  v[0] = a.x; v[1] = a.y; v[2] = a.z; v[3] = a.w;
  v[4] = b.x; v[5] = b.y; v[6] = b.z; v[7] = b.w;
}

// ---------------------------------------------------------------- prep
__global__ __launch_bounds__(256) void prep_k(
    const float* __restrict__ W, const float* __restrict__ V,
    const float* __restrict__ L, const float* __restrict__ Lm,
    unsigned short* __restrict__ Wbt, unsigned short* __restrict__ Wb2,
    unsigned short* __restrict__ Vbt, float* __restrict__ Mc,
    float* __restrict__ ssq)
{
  int idx = blockIdx.x * 256 + threadIdx.x;      // 0 .. 512*512-1
  int n = idx >> 9, k = idx & 511;
  Wbt[idx] = f2bf(W[k * D + n]);                 // G1 B^T:  Wbt[n][k] = W[k][n]
  Wb2[idx] = f2bf(W[idx]);                       // G2 B^T:  W[n][k] as-is
  Vbt[idx] = f2bf(V[k * D + n]);                 // G3 B^T:  V[k][n]
  if (idx < D * 7) {                             // lateral band: col n, j = n-3+t
    int nn = idx / 7, t = idx - nn * 7;
    int j = nn - 3 + t;
    float v = 0.f;
    if (j >= 0 && j < D && j != nn) v = L[j * D + nn] * Lm[j * D + nn];
    Mc[idx] = v;
  }
  if (idx == 0) *ssq = 0.f;
}

// ---------------------------------------------------------------- kwta + phi + base
__global__ __launch_bounds__(256) void kwta_k(
    const float* __restrict__ x, const float* __restrict__ td,
    const float* __restrict__ bu, const float* __restrict__ b_in,
    const float* __restrict__ Mc,
    unsigned short* __restrict__ phi16, unsigned short* __restrict__ pd16,
    unsigned short* __restrict__ base16, unsigned short* __restrict__ bu16)
{
  __shared__ float phibuf[4][D];
  const int tid = threadIdx.x, lane = tid & 63, wv = tid >> 6;
  const int row = blockIdx.x * 4 + wv;
  const size_t rbase = (size_t)row * D;

  float xv[8];
  load8(x + rbase, lane, xv);
  unsigned key[8];
  #pragma unroll
  for (int s = 0; s < 8; ++s) {                   // order-preserving uint keys
    unsigned u = __float_as_uint(xv[s]);
    key[s] = (u & 0x80000000u) ? ~u : (u | 0x80000000u);
  }
  // threshold key T = 128th largest: max T with count(key>=T) >= 128
  unsigned T = 0u;
  for (int bit = 31; bit >= 0; --bit) {
    unsigned cand = T | (1u << bit);
    int c = 0;
    #pragma unroll
    for (int s = 0; s < 8; ++s) c += (key[s] >= cand);
    if (wsum(c) >= 128) T = cand;
  }
  int cg = 0;
  #pragma unroll
  for (int s = 0; s < 8; ++s) cg += (key[s] > T);
  const int rneed = 128 - wsum(cg);               // how many ties to keep (lowest idx first)
  bool eq[8]; int le = 0;
  #pragma unroll
  for (int s = 0; s < 8; ++s) { eq[s] = (key[s] == T); le += eq[s] ? 1 : 0; }
  int pre = le;                                   // inclusive lane prefix of tie counts
  for (int o = 1; o < 64; o <<= 1) { int v = __shfl_up(pre, o, 64); if (lane >= o) pre += v; }
  int run = pre - le;                             // ties before my first element

  float phiv[8], pdv[8];
  float* pb = phibuf[wv];
  #pragma unroll
  for (int s = 0; s < 8; ++s) {
    bool sel = key[s] > T;
    if (eq[s]) { sel = (run < rneed); ++run; }
    float v = xv[s];
    float cdf = 0.5f * (1.0f + erff(v * 0.7071067811865476f));
    float ph = sel ? v * cdf : 0.0f;
    float pd = sel ? (cdf + v * 0.3989422804014327f * __expf(-0.5f * v * v)) : 0.0f;
    phiv[s] = ph; pdv[s] = pd;
    pb[lane * 8 + s] = ph;
  }
  __syncthreads();                                // phi row visible for lateral reads

  float tdv[8], buv[8];
  load8(td + rbase, lane, tdv);
  load8(bu + rbase, lane, buv);

  short8 o_phi, o_pd, o_base, o_bu;
  #pragma unroll
  for (int s = 0; s < 8; ++s) {
    int n = lane * 8 + s;
    float lat = 0.f;
    #pragma unroll
    for (int t = 0; t < 7; ++t) {
      int j = n - 3 + t;
      int jc = j < 0 ? 0 : (j > D - 1 ? D - 1 : j);   // Mc==0 at OOB, clamp is safe
      lat += Mc[n * 7 + t] * pb[jc];
    }
    float v = xv[s];
    float sgn = (v > 0.f) ? 1.f : ((v < 0.f) ? -1.f : 0.f);
    float bs = b_in[n] + 3.f * tdv[s] - 4.f * v + 0.3f * lat - 1e-6f * sgn;
    o_phi[s] = (short)f2bf(phiv[s]);
    o_pd[s]  = (short)f2bf(pdv[s]);
    o_base[s]= (short)f2bf(bs);
    o_bu[s]  = (short)f2bf(buv[s]);
  }
  *(short8*)(phi16 + rbase + lane * 8) = o_phi;
  *(short8*)(pd16  + rbase + lane * 8) = o_pd;
  *(short8*)(base16+ rbase + lane * 8) = o_base;
  *(short8*)(bu16  + rbase + lane * 8) = o_bu;
}

// ---------------------------------------------------------------- GEMM (m97 structure)
// C[b,n] = sum_k A[b,k]*Bt[n,k]; 128x128 tile, BK=32, 4 waves of 4x4 16x16x32 frags.
template<int MODE>
__global__ __launch_bounds__(256) void gemm_k(
    const unsigned short* __restrict__ A,    // [16384][512] bf16
    const unsigned short* __restrict__ Bt,   // [512][512] bf16 (pre-transposed)
    const float* __restrict__ f32a,          // M1: bottom_up
    const float* __restrict__ f32b,          // M1: b_out_snap
    const unsigned short* __restrict__ b16a, // M2: pd16 ; M3: fb16
    const unsigned short* __restrict__ b16b, // M3: base16
    unsigned short* __restrict__ out16,      // M1: err16 ; M2: fb16
    float* __restrict__ outf,                // M3: d (d_out)
    float* __restrict__ ssq,                 // M3
    const int* __restrict__ stepi)           // M3
{
  constexpr int K = 512;
  __shared__ __align__(16) unsigned short As[128 * 32];
  __shared__ __align__(16) unsigned short Bs[128 * 32];
  const int tid = threadIdx.x;
  const int lane = tid & 63, w = tid >> 6;
  const int m0 = (blockIdx.x >> 2) * 128, n0 = (blockIdx.x & 3) * 128;
  const int qr = (w >> 1) * 64, qc = (w & 1) * 64;
  const int lr = lane & 15, g = lane >> 4;

  f32x4 acc[4][4];
  #pragma unroll
  for (int m = 0; m < 4; ++m)
    #pragma unroll
    for (int n = 0; n < 4; ++n) acc[m][n] = (f32x4){0.f, 0.f, 0.f, 0.f};

  const unsigned short* Abase = A + (size_t)m0 * K;
  const unsigned short* Bbase = Bt + (size_t)n0 * K;

  for (int kt = 0; kt < K; kt += 32) {
    #pragma unroll
    for (int p = 0; p < 2; ++p) {                 // stage 128x32 bf16 tiles (8KB each)
      int ch = tid + p * 256;                     // 16B chunk id; 4 chunks per row
      int row = ch >> 2, kc = (ch & 3) * 8;
      gload16(Abase + (size_t)row * K + kt + kc, As + (size_t)(w * 64 + p * 256) * 8);
      gload16(Bbase + (size_t)row * K + kt + kc, Bs + (size_t)(w * 64 + p * 256) * 8);
    }
    __syncthreads();                              // compiler drains vmcnt before barrier
    short8 af[4], bfr[4];
    #pragma unroll
    for (int m = 0; m < 4; ++m) af[m]  = *(const short8*)(As + (qr + 16 * m + lr) * 32 + 8 * g);
    #pragma unroll
    for (int n = 0; n < 4; ++n) bfr[n] = *(const short8*)(Bs + (qc + 16 * n + lr) * 32 + 8 * g);
    #pragma unroll
    for (int m = 0; m < 4; ++m)
      #pragma unroll
      for (int n = 0; n < 4; ++n)
        acc[m][n] = __builtin_amdgcn_mfma_f32_16x16x32_bf16(af[m], bfr[n], acc[m][n], 0, 0, 0);
    __syncthreads();
  }

  float tau_eta = 0.f, lssq = 0.f;
  if constexpr (MODE == 3) tau_eta = 0.5f * 0.8f / (1.0f + 0.1f * (float)stepi[0]);
  #pragma unroll
  for (int m = 0; m < 4; ++m) {
    #pragma unroll
    for (int n = 0; n < 4; ++n) {
      #pragma unroll
      for (int r = 0; r < 4; ++r) {
        int row = m0 + qr + 16 * m + 4 * g + r;   // C/D: col=lane&15, row=4*(lane>>4)+reg
        int col = n0 + qc + 16 * n + lr;
        size_t idx = (size_t)row * D + col;
        float v = acc[m][n][r];
        if constexpr (MODE == 1) {
          out16[idx] = f2bf(f32a[idx] - (v + f32b[col]));
        } else if constexpr (MODE == 2) {
          out16[idx] = f2bf(v * bf2f(b16a[idx]));
        } else {
          float dv = tau_eta * (v + bf2f(b16a[idx]) + bf2f(b16b[idx]));
          outf[idx] = dv;
          lssq += dv * dv;
        }
      }
    }
  }
  if constexpr (MODE == 3) {
    lssq = wsumf(lssq);
    if (lane == 0) atomicAdd(ssq, lssq);
  }
}

// ---------------------------------------------------------------- final scale+clamp
__global__ __launch_bounds__(256) void final_k(const float* __restrict__ x,
                                               float* __restrict__ d,
                                               const float* __restrict__ ssq)
{
  float nrm = sqrtf(*ssq);
  float s = nrm > 1.0f ? 1.0f / (nrm + 1e-8f) : 1.0f;
  int i = blockIdx.x * 256 + threadIdx.x;
  const float4* xq = (const float4*)x;
  float4* dq = (float4*)d;
  float4 xv = xq[i], dv = dq[i];
  float4 o;
  o.x = fminf(fmaxf(xv.x + s * dv.x, -5.f), 5.f);
  o.y = fminf(fmaxf(xv.y + s * dv.y, -5.f), 5.f);
  o.z = fminf(fmaxf(xv.z + s * dv.z, -5.f), 5.f);
  o.w = fminf(fmaxf(xv.w + s * dv.w, -5.f), 5.f);
  dq[i] = o;
}

// ---------------------------------------------------------------- launch
extern "C" void kernel_launch(void* const* d_in, const int* in_sizes, int n_in,
                              void* d_out, int out_size, void* d_ws, size_t ws_size,
                              hipStream_t stream) {
  const float* bu    = (const float*)d_in[0];
  const float* td    = (const float*)d_in[1];
  const float* x     = (const float*)d_in[2];
  const float* V     = (const float*)d_in[3];
  const float* b_in  = (const float*)d_in[4];
  const float* W     = (const float*)d_in[5];
  const float* bout  = (const float*)d_in[6];
  const float* L     = (const float*)d_in[7];
  const float* Lm    = (const float*)d_in[8];
  const int*   stepi = (const int*)d_in[9];
  float* dout = (float*)d_out;

  char* p = (char*)d_ws;
  size_t off = 0;
  auto take = [&](size_t bytes) -> void* {
    void* r = (void*)(p + off);
    off += (bytes + 255) & ~(size_t)255;
    return r;
  };
  float* ssq            = (float*)take(4);
  unsigned short* Wbt   = (unsigned short*)take((size_t)D * D * 2);
  unsigned short* Wb2   = (unsigned short*)take((size_t)D * D * 2);
  unsigned short* Vbt   = (unsigned short*)take((size_t)D * D * 2);
  float* Mc             = (float*)take((size_t)D * 7 * 4);
  const size_t bd = (size_t)BATCH * D * 2;
  unsigned short* phi16 = (unsigned short*)take(bd);
  unsigned short* bu16  = (unsigned short*)take(bd);
  unsigned short* pd16  = (unsigned short*)take(bd);
  unsigned short* bse16 = (unsigned short*)take(bd);
  unsigned short* err16 = (unsigned short*)take(bd);
  unsigned short* fb16  = phi16;   // phi dead after G1; reuse for fb

  prep_k<<<(D * D) / 256, 256, 0, stream>>>(W, V, L, Lm, Wbt, Wb2, Vbt, Mc, ssq);
  kwta_k<<<BATCH / 4, 256, 0, stream>>>(x, td, bu, b_in, Mc, phi16, pd16, bse16, bu16);
  gemm_k<1><<<(BATCH / 128) * (D / 128), 256, 0, stream>>>(
      phi16, Wbt, bu, bout, nullptr, nullptr, err16, nullptr, nullptr, nullptr);
  gemm_k<2><<<(BATCH / 128) * (D / 128), 256, 0, stream>>>(
      err16, Wb2, nullptr, nullptr, pd16, nullptr, fb16, nullptr, nullptr, nullptr);
  gemm_k<3><<<(BATCH / 128) * (D / 128), 256, 0, stream>>>(
      bu16, Vbt, nullptr, nullptr, fb16, bse16, nullptr, dout, ssq, stepi);
  final_k<<<(BATCH * D / 4) / 256, 256, 0, stream>>>(x, dout, ssq);
}

// Round 2
// 263.441 us; speedup vs baseline: 1.0747x; 1.0747x over previous
//
#include <hip/hip_runtime.h>
#include <hip/hip_bf16.h>
#include <cstdint>

// PredictiveColumn: B=16384, DIN=DOUT=512, K_WTA=128, LATERAL_K=3
// Pipeline:
//   prep_k : bf16 convert W^T, W, V^T ; lateral band Mc7[7][512]; zero ssq
//   kwta_k : per-row (1 wave/row) top-128 via ballot binary search (exact top_k
//            tie-break), phi=gelu*mask, pd=phi', base = b_in+3td-4x+0.3*lat-1e-6*sign
//   gemm_k<1>: err = bf16(bu - (phi@W + b_out))
//   gemm_k<2>: fb  = bf16((err@W^T) * pd)
//   gemm_k<3>: d   = tau*eta*((bu@V) + fb + base) -> d_out, ssq += d^2
//   final_k: out = clamp(x + d*min(1,1/(||d||+1e-8)), -5, 5)   (in-place on d_out)

#define DEV static __device__ __forceinline__

typedef __attribute__((ext_vector_type(8))) short short8;   // 8 bf16 (4 VGPRs)
typedef __attribute__((ext_vector_type(4))) float f32x4;

static constexpr int BATCH = 16384;
static constexpr int D = 512;

DEV unsigned short f2bf(float f) {           // RNE float->bf16 (no NaN inputs here)
  unsigned u = __float_as_uint(f);
  return (unsigned short)((u + 0x7FFFu + ((u >> 16) & 1u)) >> 16);
}
DEV float bf2f(unsigned short h) { return __uint_as_float(((unsigned)h) << 16); }

DEV float wsumf(float v) { for (int o = 32; o; o >>= 1) v += __shfl_xor(v, o, 64); return v; }

DEV void gload16(const void* g, void* l) {
  __builtin_amdgcn_global_load_lds((const __attribute__((address_space(1))) void*)g,
                                   (__attribute__((address_space(3))) void*)l, 16, 0, 0);
}

DEV void load8(const float* rowp, int lane, float v[8]) {
  const float4* q = (const float4*)rowp;
  float4 a = q[lane * 2], b = q[lane * 2 + 1];
  v[0] = a.x; v[1] = a.y; v[2] = a.z; v[3] = a.w;
  v[4] = b.x; v[5] = b.y; v[6] = b.z; v[7] = b.w;
}

// ---------------------------------------------------------------- prep
__global__ __launch_bounds__(256) void prep_k(
    const float* __restrict__ W, const float* __restrict__ V,
    const float* __restrict__ L, const float* __restrict__ Lm,
    unsigned short* __restrict__ Wbt, unsigned short* __restrict__ Wb2,
    unsigned short* __restrict__ Vbt, float* __restrict__ Mc7,
    float* __restrict__ ssq)
{
  int idx = blockIdx.x * 256 + threadIdx.x;      // 0 .. 512*512-1
  int n = idx >> 9, k = idx & 511;
  Wbt[idx] = f2bf(W[k * D + n]);                 // G1 B^T:  Wbt[n][k] = W[k][n]
  Wb2[idx] = f2bf(W[idx]);                       // G2 B^T:  W[n][k] as-is
  Vbt[idx] = f2bf(V[k * D + n]);                 // G3 B^T:  V[k][n]
  if (idx < 7 * D) {                             // lateral band, layout [t][n]
    int t = idx >> 9, nn = idx & 511;
    int j = nn - 3 + t;
    float v = 0.f;
    if (j >= 0 && j < D && j != nn) v = L[j * D + nn] * Lm[j * D + nn];
    Mc7[idx] = v;
  }
  if (idx == 0) *ssq = 0.f;
}

// ---------------------------------------------------------------- kwta + phi + base
__global__ __launch_bounds__(256) void kwta_k(
    const float* __restrict__ x, const float* __restrict__ td,
    const float* __restrict__ bu, const float* __restrict__ b_in,
    const float* __restrict__ Mc7,
    unsigned short* __restrict__ phi16, unsigned short* __restrict__ pd16,
    unsigned short* __restrict__ base16, unsigned short* __restrict__ bu16)
{
  __shared__ float pbuf[4][D];                    // layout [(n&7)][n>>3] : bank-safe
  const int tid = threadIdx.x, lane = tid & 63, wv = tid >> 6;
  const int row = blockIdx.x * 4 + wv;
  const size_t rbase = (size_t)row * D;

  float xv[8];
  load8(x + rbase, lane, xv);
  unsigned key[8];
  #pragma unroll
  for (int s = 0; s < 8; ++s) {                   // order-preserving uint keys
    unsigned u = __float_as_uint(xv[s]);
    key[s] = (u & 0x80000000u) ? ~u : (u | 0x80000000u);
  }
  // threshold key T = 128th largest: max T with count(key>=T) >= 128.
  // ballot (v_cmp -> sgpr pair) + scalar popcount: no DS ops, no shuffles.
  unsigned T = 0u;
  for (int bit = 31; bit >= 0; --bit) {
    unsigned cand = T | (1u << bit);
    int c = 0;
    #pragma unroll
    for (int s = 0; s < 8; ++s) c += (int)__popcll(__ballot(key[s] >= cand));
    T = (c >= 128) ? cand : T;                    // uniform select
  }
  int cg = 0;
  unsigned long long em[8];
  #pragma unroll
  for (int s = 0; s < 8; ++s) {
    cg += (int)__popcll(__ballot(key[s] > T));
    em[s] = __ballot(key[s] == T);
  }
  const int rneed = 128 - cg;                     // #ties kept, lowest index first
  const unsigned long long lower = (1ull << lane) - 1ull;
  int run = 0;                                    // ties in lower lanes (index-major)
  #pragma unroll
  for (int s = 0; s < 8; ++s) run += (int)__popcll(em[s] & lower);

  float phiv[8], pdv[8];
  float* pb = pbuf[wv];
  #pragma unroll
  for (int s = 0; s < 8; ++s) {
    bool sel = key[s] > T;
    if (key[s] == T) { sel = (run < rneed); ++run; }
    float v = xv[s];
    float cdf = 0.5f * (1.0f + erff(v * 0.7071067811865476f));
    float ph = sel ? v * cdf : 0.0f;
    float pd = sel ? (cdf + v * 0.3989422804014327f * __expf(-0.5f * v * v)) : 0.0f;
    phiv[s] = ph; pdv[s] = pd;
    pb[(s << 6) | lane] = ph;                     // [(n&7)][n>>3]
  }
  __syncthreads();                                // phi row visible for lateral reads

  float tdv[8], buv[8];
  load8(td + rbase, lane, tdv);
  load8(bu + rbase, lane, buv);

  float lat[8] = {0.f, 0.f, 0.f, 0.f, 0.f, 0.f, 0.f, 0.f};
  #pragma unroll
  for (int t = 0; t < 7; ++t) {                   // 14 coalesced float4 coeff loads
    const float4* mq = (const float4*)(Mc7 + t * D + lane * 8);
    float4 m0 = mq[0], m1 = mq[1];
    float mm[8] = {m0.x, m0.y, m0.z, m0.w, m1.x, m1.y, m1.z, m1.w};
    #pragma unroll
    for (int s = 0; s < 8; ++s) {
      int j = lane * 8 + s - 3 + t;
      int jc = j < 0 ? 0 : (j > D - 1 ? D - 1 : j);   // Mc7==0 at OOB, clamp safe
      lat[s] += mm[s] * pb[((jc & 7) << 6) | (jc >> 3)];
    }
  }

  short8 o_phi, o_pd, o_base, o_bu;
  #pragma unroll
  for (int s = 0; s < 8; ++s) {
    int n = lane * 8 + s;
    float v = xv[s];
    float sgn = (v > 0.f) ? 1.f : ((v < 0.f) ? -1.f : 0.f);
    float bs = b_in[n] + 3.f * tdv[s] - 4.f * v + 0.3f * lat[s] - 1e-6f * sgn;
    o_phi[s] = (short)f2bf(phiv[s]);
    o_pd[s]  = (short)f2bf(pdv[s]);
    o_base[s]= (short)f2bf(bs);
    o_bu[s]  = (short)f2bf(buv[s]);
  }
  *(short8*)(phi16 + rbase + lane * 8) = o_phi;
  *(short8*)(pd16  + rbase + lane * 8) = o_pd;
  *(short8*)(base16+ rbase + lane * 8) = o_base;
  *(short8*)(bu16  + rbase + lane * 8) = o_bu;
}

// ---------------------------------------------------------------- GEMM (m97 structure)
// C[b,n] = sum_k A[b,k]*Bt[n,k]; 128x128 tile, BK=32, 4 waves of 4x4 16x16x32 frags.
template<int MODE>
__global__ __launch_bounds__(256) void gemm_k(
    const unsigned short* __restrict__ A,    // [16384][512] bf16
    const unsigned short* __restrict__ Bt,   // [512][512] bf16 (pre-transposed)
    const float* __restrict__ f32b,          // M1: b_out_snap
    const unsigned short* __restrict__ b16a, // M1: bu16 ; M2: pd16 ; M3: fb16
    const unsigned short* __restrict__ b16b, // M3: base16
    unsigned short* __restrict__ out16,      // M1: err16 ; M2: fb16
    float* __restrict__ outf,                // M3: d (d_out)
    float* __restrict__ ssq,                 // M3
    const int* __restrict__ stepi)           // M3
{
  constexpr int K = 512;
  __shared__ __align__(16) unsigned short As[128 * 32];
  __shared__ __align__(16) unsigned short Bs[128 * 32];
  const int tid = threadIdx.x;
  const int lane = tid & 63, w = tid >> 6;
  const int m0 = (blockIdx.x >> 2) * 128, n0 = (blockIdx.x & 3) * 128;
  const int qr = (w >> 1) * 64, qc = (w & 1) * 64;
  const int lr = lane & 15, g = lane >> 4;

  f32x4 acc[4][4];
  #pragma unroll
  for (int m = 0; m < 4; ++m)
    #pragma unroll
    for (int n = 0; n < 4; ++n) acc[m][n] = (f32x4){0.f, 0.f, 0.f, 0.f};

  const unsigned short* Abase = A + (size_t)m0 * K;
  const unsigned short* Bbase = Bt + (size_t)n0 * K;

  for (int kt = 0; kt < K; kt += 32) {
    #pragma unroll
    for (int p = 0; p < 2; ++p) {                 // stage 128x32 bf16 tiles (8KB each)
      int ch = tid + p * 256;                     // 16B chunk id; 4 chunks per row
      int row = ch >> 2, kc = (ch & 3) * 8;
      gload16(Abase + (size_t)row * K + kt + kc, As + (size_t)(w * 64 + p * 256) * 8);
      gload16(Bbase + (size_t)row * K + kt + kc, Bs + (size_t)(w * 64 + p * 256) * 8);
    }
    __syncthreads();                              // compiler drains vmcnt before barrier
    short8 af[4], bfr[4];
    #pragma unroll
    for (int m = 0; m < 4; ++m) af[m]  = *(const short8*)(As + (qr + 16 * m + lr) * 32 + 8 * g);
    #pragma unroll
    for (int n = 0; n < 4; ++n) bfr[n] = *(const short8*)(Bs + (qc + 16 * n + lr) * 32 + 8 * g);
    #pragma unroll
    for (int m = 0; m < 4; ++m)
      #pragma unroll
      for (int n = 0; n < 4; ++n)
        acc[m][n] = __builtin_amdgcn_mfma_f32_16x16x32_bf16(af[m], bfr[n], acc[m][n], 0, 0, 0);
    __syncthreads();
  }

  float tau_eta = 0.f, lssq = 0.f;
  if constexpr (MODE == 3) tau_eta = 0.5f * 0.8f / (1.0f + 0.1f * (float)stepi[0]);
  #pragma unroll
  for (int m = 0; m < 4; ++m) {
    #pragma unroll
    for (int n = 0; n < 4; ++n) {
      #pragma unroll
      for (int r = 0; r < 4; ++r) {
        int row = m0 + qr + 16 * m + 4 * g + r;   // C/D: col=lane&15, row=4*(lane>>4)+reg
        int col = n0 + qc + 16 * n + lr;
        size_t idx = (size_t)row * D + col;
        float v = acc[m][n][r];
        if constexpr (MODE == 1) {
          out16[idx] = f2bf(bf2f(b16a[idx]) - (v + f32b[col]));
        } else if constexpr (MODE == 2) {
          out16[idx] = f2bf(v * bf2f(b16a[idx]));
        } else {
          float dv = tau_eta * (v + bf2f(b16a[idx]) + bf2f(b16b[idx]));
          outf[idx] = dv;
          lssq += dv * dv;
        }
      }
    }
  }
  if constexpr (MODE == 3) {
    lssq = wsumf(lssq);
    if (lane == 0) atomicAdd(ssq, lssq);
  }
}

// ---------------------------------------------------------------- final scale+clamp
__global__ __launch_bounds__(256) void final_k(const float* __restrict__ x,
                                               float* __restrict__ d,
                                               const float* __restrict__ ssq)
{
  float nrm = sqrtf(*ssq);
  float s = nrm > 1.0f ? 1.0f / (nrm + 1e-8f) : 1.0f;
  int i = blockIdx.x * 256 + threadIdx.x;
  const float4* xq = (const float4*)x;
  float4* dq = (float4*)d;
  float4 xv = xq[i], dv = dq[i];
  float4 o;
  o.x = fminf(fmaxf(xv.x + s * dv.x, -5.f), 5.f);
  o.y = fminf(fmaxf(xv.y + s * dv.y, -5.f), 5.f);
  o.z = fminf(fmaxf(xv.z + s * dv.z, -5.f), 5.f);
  o.w = fminf(fmaxf(xv.w + s * dv.w, -5.f), 5.f);
  dq[i] = o;
}

// ---------------------------------------------------------------- launch
extern "C" void kernel_launch(void* const* d_in, const int* in_sizes, int n_in,
                              void* d_out, int out_size, void* d_ws, size_t ws_size,
                              hipStream_t stream) {
  const float* bu    = (const float*)d_in[0];
  const float* td    = (const float*)d_in[1];
  const float* x     = (const float*)d_in[2];
  const float* V     = (const float*)d_in[3];
  const float* b_in  = (const float*)d_in[4];
  const float* W     = (const float*)d_in[5];
  const float* bout  = (const float*)d_in[6];
  const float* L     = (const float*)d_in[7];
  const float* Lm    = (const float*)d_in[8];
  const int*   stepi = (const int*)d_in[9];
  float* dout = (float*)d_out;

  char* p = (char*)d_ws;
  size_t off = 0;
  auto take = [&](size_t bytes) -> void* {
    void* r = (void*)(p + off);
    off += (bytes + 255) & ~(size_t)255;
    return r;
  };
  float* ssq            = (float*)take(4);
  unsigned short* Wbt   = (unsigned short*)take((size_t)D * D * 2);
  unsigned short* Wb2   = (unsigned short*)take((size_t)D * D * 2);
  unsigned short* Vbt   = (unsigned short*)take((size_t)D * D * 2);
  float* Mc7            = (float*)take((size_t)7 * D * 4);
  const size_t bd = (size_t)BATCH * D * 2;
  unsigned short* phi16 = (unsigned short*)take(bd);
  unsigned short* bu16  = (unsigned short*)take(bd);
  unsigned short* pd16  = (unsigned short*)take(bd);
  unsigned short* bse16 = (unsigned short*)take(bd);
  unsigned short* err16 = (unsigned short*)take(bd);
  unsigned short* fb16  = phi16;   // phi dead after G1; reuse for fb

  prep_k<<<(D * D) / 256, 256, 0, stream>>>(W, V, L, Lm, Wbt, Wb2, Vbt, Mc7, ssq);
  kwta_k<<<BATCH / 4, 256, 0, stream>>>(x, td, bu, b_in, Mc7, phi16, pd16, bse16, bu16);
  gemm_k<1><<<(BATCH / 128) * (D / 128), 256, 0, stream>>>(
      phi16, Wbt, bout, bu16, nullptr, err16, nullptr, nullptr, nullptr);
  gemm_k<2><<<(BATCH / 128) * (D / 128), 256, 0, stream>>>(
      err16, Wb2, nullptr, pd16, nullptr, fb16, nullptr, nullptr, nullptr);
  gemm_k<3><<<(BATCH / 128) * (D / 128), 256, 0, stream>>>(
      bu16, Vbt, nullptr, fb16, bse16, nullptr, dout, ssq, stepi);
  final_k<<<(BATCH * D / 4) / 256, 256, 0, stream>>>(x, dout, ssq);
}